// Round 6
// baseline (151.715 us; speedup 1.0000x reference)
//
#include <hip/hip_runtime.h>

typedef _Float16 h16;
typedef __attribute__((ext_vector_type(2))) _Float16 f16x2;
typedef __attribute__((ext_vector_type(4))) _Float16 f16x4;
typedef __attribute__((ext_vector_type(2))) __fp16   fp16x2n;   // native return of cvt_pkrtz
typedef __attribute__((ext_vector_type(8))) _Float16 f16x8;
typedef __attribute__((ext_vector_type(4))) float f32x4;
typedef __attribute__((ext_vector_type(4))) int   i32x4;

#define S_LEN 4096
#define NHEAD 16
#define HDIM  64
#define WIN   128
#define TQ    256
#define NQT   (S_LEN / TQ)   // 16 q-tiles
#define NCH   16    // 32-key chunks covering rel window [0, 512)
#define KSTR  72    // f16 per K row   (144 B, 16B-aligned)
#define VSTR2 40    // f16 per V^T row (80 B, 16B-aligned)
#define QSCALE 0.18033688011112042f   // h^-0.5 * log2(e); scores in log2 domain

static __device__ __forceinline__ f16x2 pk(float a, float b) {
    fp16x2n r = __builtin_amdgcn_cvt_pkrtz(a, b);
    return __builtin_bit_cast(f16x2, r);
}

static __device__ __forceinline__ f16x8 cvt8(float4 a, float4 b) {
    f16x2 p0 = pk(a.x, a.y), p1 = pk(a.z, a.w);
    f16x2 p2 = pk(b.x, b.y), p3 = pk(b.z, b.w);
    f16x8 r;
    r[0]=p0[0]; r[1]=p0[1]; r[2]=p1[0]; r[3]=p1[1];
    r[4]=p2[0]; r[5]=p2[1]; r[6]=p3[0]; r[7]=p3[1];
    return r;
}

// R6: barrier-free K-loop. R2=R3=R4=R5 (53-57us) under every pipe-level edit
// -> bottleneck is the per-iteration __syncthreads lockstep: parked masked
// waves issue nothing, so each iteration costs one chunk's full unhidden
// dependency chain. Now: whole 512-key halo staged to LDS once (rolling
// 2-deep loads, no barriers), ONE __syncthreads, then each wave free-runs
// its exact 9 chunks back-to-back. All chunk addressing/swizzles/transpose
// identical to the R5-verified code. LDS 16x(4608+5120)=155,648 B -> 1
// block/CU, 8 free-running waves; grid 512 = 2 rounds.
__global__ __launch_bounds__(512, 1)
void wattn(const float* __restrict__ Qg, const float* __restrict__ Kg,
           const float* __restrict__ Vg, float* __restrict__ Og)
{
    __shared__ h16 Khalo[NCH][32 * KSTR];    // 16 x 4608 B, [key][h]
    __shared__ h16 Vhalo[NCH][64 * VSTR2];   // 16 x 5120 B, V^T [h][key'] swizzled

    const int tid  = threadIdx.x;
    const int wid  = tid >> 6;
    const int lane = tid & 63;
    const int l15  = lane & 15;
    const int quad = lane >> 4;

    // XCD-chunked bijective swizzle (R2-verified: FETCH ~= 1x compulsory).
    int lin = blockIdx.x + NQT * (blockIdx.y + NHEAD * blockIdx.z);
    int nwg = NQT * NHEAD * gridDim.z;
    int swz = ((nwg & 7) == 0) ? ((lin & 7) * (nwg >> 3) + (lin >> 3)) : lin;
    const int bx   = swz & (NQT - 1);
    const int head = (swz / NQT) & (NHEAD - 1);
    const int b    = swz / (NQT * NHEAD);

    const int q0    = bx * TQ;
    const int kbase = q0 - WIN;
    const int rowstride = NHEAD * HDIM;   // 1024 floats between seq positions

    const float* KB = Kg + ((long)b * S_LEN * NHEAD + head) * HDIM;
    const float* VB = Vg + ((long)b * S_LEN * NHEAD + head) * HDIM;

    // staging assignment: 16 lanes cover one key row's 256 B contiguously
    const int srow = tid >> 4;            // 0..31 key-in-chunk
    const int ish  = tid & 15;            // h-quad index
    const int sh0  = ish * 4;             // h offset (x4 floats = 16 B)
    // V^T key swizzle (refchecked R1-R5): breaks the 16-way write fold.
    const int vkey = ((srow + (((ish >> 2) & 3) << 3)) & 31) ^ ((ish & 3) << 3);

    float4 ka, va, kb, vb;
    #define CLMP(x) ((x) < 0 ? 0 : ((x) > S_LEN-1 ? S_LEN-1 : (x)))
    #define SLOADA(i) do {                                                   \
        int kg_ = CLMP(kbase + (i)*32 + srow);                               \
        ka = *(const float4*)(KB + (long)kg_ * rowstride + sh0);             \
        va = *(const float4*)(VB + (long)kg_ * rowstride + sh0);             \
    } while (0)
    #define SLOADB(i) do {                                                   \
        int kg_ = CLMP(kbase + (i)*32 + srow);                               \
        kb = *(const float4*)(KB + (long)kg_ * rowstride + sh0);             \
        vb = *(const float4*)(VB + (long)kg_ * rowstride + sh0);             \
    } while (0)
    #define SWR(i, kr_, vr_) do {                                           \
        f16x2 p0_ = pk(kr_.x, kr_.y), p1_ = pk(kr_.z, kr_.w);               \
        f16x4 kv_; kv_[0]=p0_[0]; kv_[1]=p0_[1]; kv_[2]=p1_[0]; kv_[3]=p1_[1];\
        *(f16x4*)&Khalo[i][srow * KSTR + sh0] = kv_;                        \
        Vhalo[i][(sh0+0) * VSTR2 + vkey] = (h16)vr_.x;                      \
        Vhalo[i][(sh0+1) * VSTR2 + vkey] = (h16)vr_.y;                      \
        Vhalo[i][(sh0+2) * VSTR2 + vkey] = (h16)vr_.z;                      \
        Vhalo[i][(sh0+3) * VSTR2 + vkey] = (h16)vr_.w;                      \
    } while (0)

    SLOADA(0);
    SLOADB(1);

    // ---- Q fragments: TWO q-16-tiles per wave (rows wid*32 + 16*t2 + l15).
    // B-operand of the SWAPPED QK^T: mfma(K, Q) -> S^T; lane l15 owns one
    // q-row of P per tile (row-reduce and PV A-operand are lane-local).
    f16x8 aQ[2][2];
    #pragma unroll
    for (int t2 = 0; t2 < 2; ++t2) {
        const int qrow = q0 + wid*32 + t2*16 + l15;
        const float* qp = Qg + ((long)(b * S_LEN + qrow) * NHEAD + head) * HDIM;
        float4 x0 = *(const float4*)(qp + quad*8);
        float4 x1 = *(const float4*)(qp + quad*8 + 4);
        float4 x2 = *(const float4*)(qp + 32 + quad*8);
        float4 x3 = *(const float4*)(qp + 32 + quad*8 + 4);
        x0.x*=QSCALE; x0.y*=QSCALE; x0.z*=QSCALE; x0.w*=QSCALE;
        x1.x*=QSCALE; x1.y*=QSCALE; x1.z*=QSCALE; x1.w*=QSCALE;
        x2.x*=QSCALE; x2.y*=QSCALE; x2.z*=QSCALE; x2.w*=QSCALE;
        x3.x*=QSCALE; x3.y*=QSCALE; x3.z*=QSCALE; x3.w*=QSCALE;
        aQ[t2][0] = cvt8(x0, x1);
        aQ[t2][1] = cvt8(x2, x3);
    }

    // ---- whole-halo staging, rolling 2-deep, NO barriers inside ----
    #pragma unroll
    for (int p = 0; p < NCH; p += 2) {
        SWR(p, ka, va);
        if (p + 2 < NCH) SLOADA(p + 2);
        SWR(p + 1, kb, vb);
        if (p + 3 < NCH) SLOADB(p + 3);
    }
    __syncthreads();                       // the ONLY block-wide barrier
    #undef SLOADA
    #undef SLOADB
    #undef SWR
    #undef CLMP

    // per-lane window bounds, per tile (lane's q-row is l15 within tile t2)
    int lo[2]; unsigned span[2];
    #pragma unroll
    for (int t2 = 0; t2 < 2; ++t2) {
        const int qg = q0 + wid*32 + t2*16 + l15;
        lo[t2] = (qg - WIN < 0) ? 0 : qg - WIN;
        const int hi = (qg + WIN > S_LEN-1) ? S_LEN-1 : qg + WIN;
        span[t2] = (unsigned)(hi - lo[t2]);
    }

    float l_lane[2] = {0.f, 0.f};
    f32x4 Oacc[2][4];
    #pragma unroll
    for (int t2 = 0; t2 < 2; ++t2)
        #pragma unroll
        for (int t = 0; t < 4; ++t) Oacc[t2][t] = (f32x4){0.f,0.f,0.f,0.f};

    const int pxr = (l15 & 12) << 1;       // V read-side col XOR (row = l15)
    // butterfly step-2 partner: quads 1<->2 exchange (lane ^ 48), 0/3 keep
    const int xl = (quad == 1 || quad == 2) ? (lane ^ 48) : lane;

    // wave w needs keys [32w-128, 32w+159] rel kbase -> exactly chunks
    // [w, w+9) of 16. Free-running: no masked iterations, no barriers; the
    // compiler pipelines ds_reads across chunk iterations.
    #pragma unroll 3
    for (int ii = 0; ii < 9; ++ii) {
        const int i = wid + ii;
        const h16* Kb = Khalo[i];
        const h16* Vb = Vhalo[i];

        // ---- QK^T (swapped): K fragments read ONCE, used by both tiles
        f32x4 s0[2], s1[2];
        {
            f16x8 bK00 = *(const f16x8*)&Kb[ l15      * KSTR + quad*8];
            f16x8 bK01 = *(const f16x8*)&Kb[ l15      * KSTR + 32 + quad*8];
            #pragma unroll
            for (int t2 = 0; t2 < 2; ++t2) {
                f32x4 z = (f32x4){0.f,0.f,0.f,0.f};
                z = __builtin_amdgcn_mfma_f32_16x16x32_f16(bK00, aQ[t2][0], z, 0, 0, 0);
                z = __builtin_amdgcn_mfma_f32_16x16x32_f16(bK01, aQ[t2][1], z, 0, 0, 0);
                s0[t2] = z;
            }
            f16x8 bK10 = *(const f16x8*)&Kb[(16+l15)  * KSTR + quad*8];
            f16x8 bK11 = *(const f16x8*)&Kb[(16+l15)  * KSTR + 32 + quad*8];
            #pragma unroll
            for (int t2 = 0; t2 < 2; ++t2) {
                f32x4 z = (f32x4){0.f,0.f,0.f,0.f};
                z = __builtin_amdgcn_mfma_f32_16x16x32_f16(bK10, aQ[t2][0], z, 0, 0, 0);
                z = __builtin_amdgcn_mfma_f32_16x16x32_f16(bK11, aQ[t2][1], z, 0, 0, 0);
                s1[t2] = z;
            }
        }

        // ---- mask+exp2+transpose per tile (independent chains -> ILP)
        f16x8 aP[2];
        const int colb = kbase + i*32 + quad*4;
        #pragma unroll
        for (int t2 = 0; t2 < 2; ++t2) {
            float pl[4], ph[4];
            #pragma unroll
            for (int r = 0; r < 4; ++r) {
                int c_ = colb + r;
                float v0 = ((unsigned)(c_      - lo[t2]) <= span[t2]) ? s0[t2][r] : -1e30f;
                float v1 = ((unsigned)(c_ + 16 - lo[t2]) <= span[t2]) ? s1[t2][r] : -1e30f;
                pl[r] = exp2f(v0);    // exp2(-1e30)=0 -> masked cols vanish
                ph[r] = exp2f(v1);
            }
            l_lane[t2] += ((pl[0]+pl[1]) + (pl[2]+pl[3]))
                        + ((ph[0]+ph[1]) + (ph[2]+ph[3]));

            // in-register P transpose -> PV A-operand (R3-verified)
            int u0 = __builtin_bit_cast(int, pk(pl[0], pl[1]));
            int u1 = __builtin_bit_cast(int, pk(pl[2], pl[3]));
            int u2 = __builtin_bit_cast(int, pk(ph[0], ph[1]));
            int u3 = __builtin_bit_cast(int, pk(ph[2], ph[3]));
            {
                const bool q0b = (quad & 1);
                int s0w = q0b ? u0 : u2;      // q0=1 sends lo, q0=0 sends hi
                int s1w = q0b ? u1 : u3;
                int r0 = __builtin_amdgcn_ds_swizzle(s0w, 0x401F);  // lane^16
                int r1 = __builtin_amdgcn_ds_swizzle(s1w, 0x401F);
                if (q0b) { u0 = r0; u1 = r1; } else { u2 = r0; u3 = r1; }
            }
            u0 = __shfl(u0, xl);  u1 = __shfl(u1, xl);
            u2 = __shfl(u2, xl);  u3 = __shfl(u3, xl);
            i32x4 uu; uu[0]=u0; uu[1]=u1; uu[2]=u2; uu[3]=u3;
            aP[t2] = __builtin_bit_cast(f16x8, uu);  // P[l15][8*quad+0..7]
        }

        // ---- PV: V fragments read ONCE, used by both tiles
        #pragma unroll
        for (int t = 0; t < 4; ++t) {
            // invert V key swizzle: rot by t (h bits 4-5), XOR by l15>>2
            f16x8 bV = *(const f16x8*)&Vb[(t*16 + l15) * VSTR2 +
                                          (((quad*8 + (t << 3)) & 31) ^ pxr)];
            Oacc[0][t] = __builtin_amdgcn_mfma_f32_16x16x32_f16(aP[0], bV, Oacc[0][t], 0, 0, 0);
            Oacc[1][t] = __builtin_amdgcn_mfma_f32_16x16x32_f16(aP[1], bV, Oacc[1][t], 0, 0, 0);
        }
    }

    // ---- epilogue per tile: l lives per-lane (row q=l15); reduce over quads
    #pragma unroll
    for (int t2 = 0; t2 < 2; ++t2) {
        float l = l_lane[t2];
        l += __shfl_xor(l, 16);
        l += __shfl_xor(l, 32);
        const float inv = 1.0f / l;        // lane (q, any quad) holds row-q inv

        float* op = Og + ((long)(b * S_LEN + q0 + wid*32 + t2*16) * NHEAD + head) * HDIM;
        #pragma unroll
        for (int r = 0; r < 4; ++r) {
            float invr = __shfl(inv, quad*4 + r);
            #pragma unroll
            for (int t = 0; t < 4; ++t) {
                op[(quad*4 + r) * rowstride + t*16 + l15] = Oacc[t2][t][r] * invr;
            }
        }
    }
}

extern "C" void kernel_launch(void* const* d_in, const int* in_sizes, int n_in,
                              void* d_out, int out_size, void* d_ws, size_t ws_size,
                              hipStream_t stream) {
    const float* q = (const float*)d_in[0];
    const float* k = (const float*)d_in[1];
    const float* v = (const float*)d_in[2];
    float* out = (float*)d_out;
    const int batch = in_sizes[0] / (S_LEN * NHEAD * HDIM);
    dim3 grid(NQT, NHEAD, batch);
    wattn<<<grid, 512, 0, stream>>>(q, k, v, out);
}

// Round 7
// 145.818 us; speedup vs baseline: 1.0404x; 1.0404x over previous
//
#include <hip/hip_runtime.h>

typedef _Float16 h16;
typedef __attribute__((ext_vector_type(2))) _Float16 f16x2;
typedef __attribute__((ext_vector_type(4))) _Float16 f16x4;
typedef __attribute__((ext_vector_type(2))) __fp16   fp16x2n;   // native return of cvt_pkrtz
typedef __attribute__((ext_vector_type(8))) _Float16 f16x8;
typedef __attribute__((ext_vector_type(4))) float f32x4;
typedef __attribute__((ext_vector_type(4))) int   i32x4;

#define S_LEN 4096
#define NHEAD 16
#define HDIM  64
#define WIN   128
#define TQ    128
#define NQT   (S_LEN / TQ)   // 32 q-tiles
#define NPH   6     // phases of 64 keys; rel window [0, 384) = 12 chunks of 32
#define KSTR  72    // f16 per K row   (144 B, 16B-aligned)
#define VSTR2 40    // f16 per V^T row (80 B, 16B-aligned)
#define QSCALE 0.18033688011112042f   // h^-0.5 * log2(e); scores in log2 domain

static __device__ __forceinline__ f16x2 pk(float a, float b) {
    fp16x2n r = __builtin_amdgcn_cvt_pkrtz(a, b);
    return __builtin_bit_cast(f16x2, r);
}

// R7: exp2f without fast-math lowers to the OCML correctly-rounded routine
// (multi-instr denormal fixup) -- on the critical chain 8-16x per chunk.
// Raw v_exp_f32 is 1 instr, ~1 ULP; absmax budget 0.0078 >> that, and
// v_exp_f32(-1e30) = 0 keeps the masked-lane semantics.
static __device__ __forceinline__ float ex2(float x) {
    float r; asm("v_exp_f32 %0, %1" : "=v"(r) : "v"(x)); return r;
}

static __device__ __forceinline__ f16x8 cvt8(float4 a, float4 b) {
    f16x2 p0 = pk(a.x, a.y), p1 = pk(a.z, a.w);
    f16x2 p2 = pk(b.x, b.y), p3 = pk(b.z, b.w);
    f16x8 r;
    r[0]=p0[0]; r[1]=p0[1]; r[2]=p1[0]; r[3]=p1[1];
    r[4]=p2[0]; r[5]=p2[1]; r[6]=p3[0]; r[7]=p3[1];
    return r;
}

// R7 = R4 base (best measured, 53.4us) + native exp2 + maskless interior
// chunks + setprio around MFMA. R2-R6 established: DS traffic, barrier count,
// P round-trip, HBM all null; occupancy drop hurts -> latency-bound on the
// per-wave VALU chain (VALUBusy 33% = 3-4x hand-count -> hidden VALU).
// (512,4): 128-VGPR budget, 4 blocks/CU. LDS 4 x 38912 = 155.6 KB <= 160 KB.
__global__ __launch_bounds__(512, 4)
void wattn(const float* __restrict__ Qg, const float* __restrict__ Kg,
           const float* __restrict__ Vg, float* __restrict__ Og)
{
    // [dbuf][sub]: strides/swizzles identical to the R3-verified 32-key panels
    __shared__ h16 Kbuf[2][2][32 * KSTR];   // 4 x 4608 B, [key][h]
    __shared__ h16 Vbuf[2][2][64 * VSTR2];  // 4 x 5120 B, V^T [h][key'] swizzled

    const int tid  = threadIdx.x;
    const int wid  = tid >> 6;
    const int lane = tid & 63;
    const int l15  = lane & 15;
    const int quad = lane >> 4;

    // XCD-chunked bijective swizzle: each XCD owns 128 consecutive blocks =
    // 4 whole (head,b) K/V panels -> halo re-reads hit that XCD's L2.
    // (R2-R6 measured FETCH ~= 1x compulsory traffic: it works.)
    int lin = blockIdx.x + NQT * (blockIdx.y + NHEAD * blockIdx.z);
    int nwg = NQT * NHEAD * gridDim.z;
    int swz = ((nwg & 7) == 0) ? ((lin & 7) * (nwg >> 3) + (lin >> 3)) : lin;
    const int bx   = swz & (NQT - 1);
    const int head = (swz / NQT) & (NHEAD - 1);
    const int b    = swz / (NQT * NHEAD);

    const int q0    = bx * TQ;
    const int kbase = q0 - WIN;
    const int rowstride = NHEAD * HDIM;   // 1024 floats between seq positions
    // blocks where sequence-edge clamping can reach an interior chunk
    const bool edgeblk = (bx == 0) | (bx == NQT - 1);

    const float* KB = Kg + ((long)b * S_LEN * NHEAD + head) * HDIM;
    const float* VB = Vg + ((long)b * S_LEN * NHEAD + head) * HDIM;

    // staging assignment: 16 lanes cover one key row's 256 B contiguously;
    // each thread stages the same row slot in BOTH 32-key sub-chunks.
    const int srow = tid >> 4;            // 0..31 key-in-subchunk
    const int ish  = tid & 15;            // h-quad index
    const int sh0  = ish * 4;             // h offset (x4 floats = 16 B)
    // V^T key swizzle (refchecked R1-R6): breaks the 16-way write fold.
    const int vkey = ((srow + (((ish >> 2) & 3) << 3)) & 31) ^ ((ish & 3) << 3);

    float4 kreg0, vreg0, kreg1, vreg1;
    #define CLMP(x) ((x) < 0 ? 0 : ((x) > S_LEN-1 ? S_LEN-1 : (x)))
    #define SLOAD(p) do {                                                    \
        int g0_ = CLMP(kbase + (p)*64 + srow);                               \
        int g1_ = CLMP(kbase + (p)*64 + 32 + srow);                          \
        kreg0 = *(const float4*)(KB + (long)g0_ * rowstride + sh0);          \
        vreg0 = *(const float4*)(VB + (long)g0_ * rowstride + sh0);          \
        kreg1 = *(const float4*)(KB + (long)g1_ * rowstride + sh0);          \
        vreg1 = *(const float4*)(VB + (long)g1_ * rowstride + sh0);          \
    } while (0)
    #define SWR1(bi_, s_, kr_, vr_) do {                                     \
        f16x2 ka_ = pk(kr_.x, kr_.y), kb_ = pk(kr_.z, kr_.w);                \
        f16x4 kv_; kv_[0]=ka_[0]; kv_[1]=ka_[1]; kv_[2]=kb_[0]; kv_[3]=kb_[1];\
        *(f16x4*)&Kbuf[bi_][s_][srow * KSTR + sh0] = kv_;                    \
        Vbuf[bi_][s_][(sh0+0) * VSTR2 + vkey] = (h16)vr_.x;                  \
        Vbuf[bi_][s_][(sh0+1) * VSTR2 + vkey] = (h16)vr_.y;                  \
        Vbuf[bi_][s_][(sh0+2) * VSTR2 + vkey] = (h16)vr_.z;                  \
        Vbuf[bi_][s_][(sh0+3) * VSTR2 + vkey] = (h16)vr_.w;                  \
    } while (0)
    #define SWRITE(p) do {                                                   \
        int bi_ = (p) & 1;                                                   \
        SWR1(bi_, 0, kreg0, vreg0);                                          \
        SWR1(bi_, 1, kreg1, vreg1);                                          \
    } while (0)

    SLOAD(0);

    // ---- Q fragments (pre-scaled by h^-0.5 * log2e) ----
    // B-operand of the SWAPPED QK^T: mfma(K, Q) -> S^T; lane l15 owns one
    // q-row of P (row-reduce and PV A-operand are lane-local).
    f16x8 aQ0, aQ1;
    {
        const int qrow = q0 + wid * 16 + l15;
        const float* qp = Qg + ((long)(b * S_LEN + qrow) * NHEAD + head) * HDIM;
        float4 x0 = *(const float4*)(qp + quad*8);
        float4 x1 = *(const float4*)(qp + quad*8 + 4);
        float4 x2 = *(const float4*)(qp + 32 + quad*8);
        float4 x3 = *(const float4*)(qp + 32 + quad*8 + 4);
        x0.x*=QSCALE; x0.y*=QSCALE; x0.z*=QSCALE; x0.w*=QSCALE;
        x1.x*=QSCALE; x1.y*=QSCALE; x1.z*=QSCALE; x1.w*=QSCALE;
        x2.x*=QSCALE; x2.y*=QSCALE; x2.z*=QSCALE; x2.w*=QSCALE;
        x3.x*=QSCALE; x3.y*=QSCALE; x3.z*=QSCALE; x3.w*=QSCALE;
        aQ0 = cvt8(x0, x1);
        aQ1 = cvt8(x2, x3);
    }

    SWRITE(0);
    SLOAD(1);          // in flight across the barrier; written at phase-0 start
    __syncthreads();

    // per-lane window bounds (lane's q-row is l15)
    const int qg = q0 + wid*16 + l15;
    const int lo = (qg - WIN < 0) ? 0 : qg - WIN;
    const int hi = (qg + WIN > S_LEN-1) ? S_LEN-1 : qg + WIN;
    const unsigned span = (unsigned)(hi - lo);

    float l_lane = 0.f;
    f32x4 Oacc[4];
    #pragma unroll
    for (int t = 0; t < 4; ++t) Oacc[t] = (f32x4){0.f,0.f,0.f,0.f};

    // wave w truly needs chunks [m, m+9), m = w>>1; widened to even-aligned
    // phases [w>>2, w>>2+5) = 10 chunks. Extra chunk fully masked (p=0).
    // Chunks (m, m+8) are in-window for ALL 32 of the wave's rows (verified
    // for both wave parities) -> maskless fast path on interior blocks.
    const int pc0 = wid >> 2;
    const int m_  = wid >> 1;
    const int pxr = (l15 & 12) << 1;       // V read-side col XOR (row = l15)
    // butterfly step-2 partner: quads 1<->2 exchange (lane ^ 48), 0/3 keep
    const int xl = (quad == 1 || quad == 2) ? (lane ^ 48) : lane;

    for (int ph = 0; ph < NPH; ++ph) {
        // SWRITE(ph+1)'s vmcnt wait covers loads issued a full phase ago;
        // SLOAD(ph+2) stays in flight across this phase's compute + barrier.
        if (ph + 1 < NPH) SWRITE(ph + 1);
        if (ph + 2 < NPH) SLOAD(ph + 2);

        if ((unsigned)(ph - pc0) < 5u) {
            #pragma unroll
            for (int s = 0; s < 2; ++s) {
                const h16* Kb = Kbuf[ph & 1][s];
                const h16* Vb = Vbuf[ph & 1][s];
                const int i = 2*ph + s;
                const bool nomask = (!edgeblk) & (i > m_) & (i < m_ + 8);

                f16x8 bK00 = *(const f16x8*)&Kb[ l15      * KSTR + quad*8];
                f16x8 bK01 = *(const f16x8*)&Kb[ l15      * KSTR + 32 + quad*8];
                f16x8 bK10 = *(const f16x8*)&Kb[(16+l15)  * KSTR + quad*8];
                f16x8 bK11 = *(const f16x8*)&Kb[(16+l15)  * KSTR + 32 + quad*8];

                // swapped QK^T: S^T[key][q].  Lane (l15,quad):
                //   s0[r] = S[q=l15][k = 4*quad + r],  s1[r] = same + 16
                __builtin_amdgcn_s_setprio(1);
                f32x4 s0 = (f32x4){0.f,0.f,0.f,0.f};
                s0 = __builtin_amdgcn_mfma_f32_16x16x32_f16(bK00, aQ0, s0, 0, 0, 0);
                s0 = __builtin_amdgcn_mfma_f32_16x16x32_f16(bK01, aQ1, s0, 0, 0, 0);
                f32x4 s1 = (f32x4){0.f,0.f,0.f,0.f};
                s1 = __builtin_amdgcn_mfma_f32_16x16x32_f16(bK10, aQ0, s1, 0, 0, 0);
                s1 = __builtin_amdgcn_mfma_f32_16x16x32_f16(bK11, aQ1, s1, 0, 0, 0);
                __builtin_amdgcn_s_setprio(0);

                const int colb = kbase + i*32 + quad*4;
                float pl[4], phh[4];
                if (nomask) {
                    // interior chunk: every key in-window for all lanes
                    #pragma unroll
                    for (int r = 0; r < 4; ++r) {
                        pl[r]  = ex2(s0[r]);
                        phh[r] = ex2(s1[r]);
                    }
                } else {
                    #pragma unroll
                    for (int r = 0; r < 4; ++r) {
                        int c_ = colb + r;
                        float v0 = ((unsigned)(c_      - lo) <= span) ? s0[r] : -1e30f;
                        float v1 = ((unsigned)(c_ + 16 - lo) <= span) ? s1[r] : -1e30f;
                        pl[r]  = ex2(v0);   // exp2(-1e30)=0 -> masked cols vanish
                        phh[r] = ex2(v1);
                    }
                }
                l_lane += ((pl[0]+pl[1]) + (pl[2]+pl[3]))
                        + ((phh[0]+phh[1]) + (phh[2]+phh[3]));

                // ---- in-register P transpose -> PV A-operand (R3-verified) ----
                int u0 = __builtin_bit_cast(int, pk(pl[0],  pl[1]));
                int u1 = __builtin_bit_cast(int, pk(pl[2],  pl[3]));
                int u2 = __builtin_bit_cast(int, pk(phh[0], phh[1]));
                int u3 = __builtin_bit_cast(int, pk(phh[2], phh[3]));
                {
                    const bool q0b = (quad & 1);
                    int s0w = q0b ? u0 : u2;      // q0=1 sends lo, q0=0 sends hi
                    int s1w = q0b ? u1 : u3;
                    int r0 = __builtin_amdgcn_ds_swizzle(s0w, 0x401F);  // lane^16
                    int r1 = __builtin_amdgcn_ds_swizzle(s1w, 0x401F);
                    if (q0b) { u0 = r0; u1 = r1; } else { u2 = r0; u3 = r1; }
                }
                u0 = __shfl(u0, xl);  u1 = __shfl(u1, xl);
                u2 = __shfl(u2, xl);  u3 = __shfl(u3, xl);
                i32x4 uu; uu[0]=u0; uu[1]=u1; uu[2]=u2; uu[3]=u3;
                f16x8 aP = __builtin_bit_cast(f16x8, uu);  // P[l15][8*quad+0..7]

                __builtin_amdgcn_s_setprio(1);
                #pragma unroll
                for (int t = 0; t < 4; ++t) {
                    // invert V key swizzle: rot by t (h bits 4-5), XOR by l15>>2
                    f16x8 bV = *(const f16x8*)&Vb[(t*16 + l15) * VSTR2 +
                                                  (((quad*8 + (t << 3)) & 31) ^ pxr)];
                    Oacc[t] = __builtin_amdgcn_mfma_f32_16x16x32_f16(aP, bV, Oacc[t], 0, 0, 0);
                }
                __builtin_amdgcn_s_setprio(0);
            }
        }

        __syncthreads();                   // one barrier per 64-key phase
    }
    #undef SLOAD
    #undef SWRITE
    #undef SWR1
    #undef CLMP

    // ---- epilogue: l lives per-lane (row q=l15); reduce across quads ----
    float l = l_lane;
    l += __shfl_xor(l, 16);
    l += __shfl_xor(l, 32);
    const float inv = 1.0f / l;            // lane (q, any quad) holds row-q inv

    float* op = Og + ((long)(b * S_LEN + q0 + wid*16) * NHEAD + head) * HDIM;
    #pragma unroll
    for (int r = 0; r < 4; ++r) {
        float invr = __shfl(inv, quad*4 + r);
        #pragma unroll
        for (int t = 0; t < 4; ++t) {
            op[(quad*4 + r) * rowstride + t*16 + l15] = Oacc[t][r] * invr;
        }
    }
}

extern "C" void kernel_launch(void* const* d_in, const int* in_sizes, int n_in,
                              void* d_out, int out_size, void* d_ws, size_t ws_size,
                              hipStream_t stream) {
    const float* q = (const float*)d_in[0];
    const float* k = (const float*)d_in[1];
    const float* v = (const float*)d_in[2];
    float* out = (float*)d_out;
    const int batch = in_sizes[0] / (S_LEN * NHEAD * HDIM);
    dim3 grid(NQT, NHEAD, batch);
    wattn<<<grid, 512, 0, stream>>>(q, k, v, out);
}